// Round 15
// baseline (18.992 us; speedup 1.0000x reference)
//
#include <hip/hip_runtime.h>

#define B_TOTAL 4096
#define D 32
#define H 256
#define SPB 8            // real samples per block (m-rows 8..15 of MFMA unused)
#define SPBMAX 16        // MFMA m/n extent (buffers sized for 16)
#define NW 8             // waves per block
#define HPW 32           // hidden units per wave
#define PGS 34           // partG row stride (dwords)
#define XCS 40           // xcH/xcL row stride (u16)

static constexpr float EPS = 0.1f;
static constexpr float LOG2E = 1.44269504088896340736f;

typedef __attribute__((ext_vector_type(8))) short short8v;   // 8 x bf16
typedef __attribute__((ext_vector_type(4))) float f32x4;

__device__ __forceinline__ unsigned short bf16rne(float f) {
  unsigned u = __float_as_uint(f);
  u += 0x7FFFu + ((u >> 16) & 1u);
  return (unsigned short)(u >> 16);
}
__device__ __forceinline__ float fromb(unsigned short h) {
  return __uint_as_float(((unsigned)h) << 16);
}
__device__ __forceinline__ void split_rne(float f, unsigned short& hi, unsigned short& lo) {
  hi = bf16rne(f); lo = bf16rne(f - fromb(hi));
}

#define MFMA16(A, Bf, C) __builtin_amdgcn_mfma_f32_16x16x32_bf16((A), (Bf), (C), 0, 0, 0)

// k-permutations (MFMA contracts K in any order as long as A and B agree):
//   kappa(lg*8+j) = lg*4 + (j>>1) + ((j&1)<<4)   [z-pass k=d; matches xc pair layout]
//   sigma(lg*8+j) = ((j>>2)<<4) + lg*4 + (j&3)   [g-pass k=h; matches in-register a layout]

__global__ __launch_bounds__(512, 2) void ma_flow_kernel(
    const float* __restrict__ x_in, const float* __restrict__ logp_in,
    const float* __restrict__ w1, const float* __restrict__ b1,
    const float* __restrict__ w2, float* __restrict__ out)
{
  __shared__ __align__(16) float partG[NW][SPBMAX][PGS];     // per-wave partial g
  __shared__ __align__(16) unsigned short xcH[SPBMAX][XCS];  // xc hi-bf16, pair layout
  __shared__ __align__(16) unsigned short xcL[SPBMAX][XCS];  // xc lo-bf16, pair layout

  const int tid = threadIdx.x;
  const int l  = tid & 63;
  const int wv = tid >> 6;       // wave id = 32-h slice
  const int lr = l & 15;         // MFMA index lane: sample (z-out/g-A); d-col (Bg)
  const int lg = l >> 4;         // MFMA k-group
  const int hbase = wv * HPW;
  const int s_own = tid >> 5;    // owned row (0..15; rows >= SPB are dummies)
  const int d_own = tid & 31;    // owned dim
  const int xci = ((d_own & 15) << 1) | (d_own >> 4);  // u16 index in pair layout

  // ---------------- weight fragments (registers) --------------------------------
  // z-pass A=w1*log2e: A[m=h][k=d], h = hbase + tau*16 + lr, kappa k-order
  short8v Bzh[2], Bzl[2];
  float ctau[2];
#pragma unroll
  for (int tau = 0; tau < 2; ++tau) {
    const int h = hbase + tau * 16 + lr;
    float cpart = 0.0f;
    short8v hi, lo;
#pragma unroll
    for (int j = 0; j < 8; ++j) {
      const int dj = lg * 4 + (j >> 1) + ((j & 1) << 4);   // kappa
      float w = w1[dj * H + h];
      cpart = fmaf(w, w, cpart);                           // c_h from TRUE w
      unsigned short hb, lb; split_rne(w * LOG2E, hb, lb); // scaled for exp2
      hi[j] = (short)hb; lo[j] = (short)lb;
    }
    Bzh[tau] = hi; Bzl[tau] = lo;
    cpart += __shfl_xor(cpart, 16);            // sum the 4 k-groups -> c_h (h by lr)
    cpart += __shfl_xor(cpart, 32);
    ctau[tau] = cpart;
  }
  // per-lane h-tables for the swapped z output: h = hbase + tau*16 + lg*4 + r
  f32x4 b1v[2], w2v[2], w2cv[2];
#pragma unroll
  for (int tau = 0; tau < 2; ++tau)
#pragma unroll
    for (int r = 0; r < 4; ++r) {
      const int hh = hbase + tau * 16 + lg * 4 + r;
      b1v[tau][r] = b1[hh] * LOG2E;                        // scaled bias
      float w2x = w2[hh];
      w2v[tau][r] = w2x;
      w2cv[tau][r] = w2x * __shfl(ctau[tau], lg * 4 + r);  // c redistributed lr->(lg,r)
    }
  // g-pass B=w1^T (TRUE weights): B[k=h][n=d], d = nu*16 + lr, sigma k-order
  short8v Bgh[2], Bgl[2];
#pragma unroll
  for (int nu = 0; nu < 2; ++nu) {
    const int d = nu * 16 + lr;
    short8v hi, lo;
#pragma unroll
    for (int j = 0; j < 8; ++j) {
      const int hl = ((j >> 2) << 4) + lg * 4 + (j & 3);   // sigma
      float w = w1[d * H + hbase + hl];
      unsigned short hb, lb; split_rne(w, hb, lb);
      hi[j] = (short)hb; lo[j] = (short)lb;
    }
    Bgh[nu] = hi; Bgl[nu] = lo;
  }

  // ---------------- state init: thread owns (s_own, d_own); dummy rows zeroed ---
  float x0r = 0.0f, accr = 0.0f, lp = 0.0f;
  if (tid < SPB * D) x0r = x_in[blockIdx.x * (SPB * D) + tid];   // coalesced
  {
    unsigned u = __float_as_uint(x0r);
    xcH[s_own][xci] = (unsigned short)(u >> 16);
    float res = x0r - __uint_as_float(u & 0xFFFF0000u);   // exact
    xcL[s_own][xci] = (unsigned short)(__float_as_uint(res) >> 16);
  }
  if (tid < SPB) lp = logp_in[blockIdx.x * SPB + tid];
  float lapAcc = 0.0f;     // wa-weighted lap partial for sample lr (this lane's 8 h's)
  __syncthreads();

  // ---------------- 8 RK4 stage evaluations -------------------------------------
#pragma unroll 1
  for (int stage = 0; stage < 8; ++stage) {
    const int st = stage & 3;
    const float wa = (st == 0 || st == 3) ? (EPS / 6.0f) : (EPS / 3.0f);
    const float wc = (st == 2) ? EPS : (EPS * 0.5f);

    // -- phase 1: swapped z-MFMAs (D[m=h][n=sample]) + sigmoid, in-register -----
    short8v xh = *reinterpret_cast<const short8v*>(&xcH[lr][lg * 8]);
    short8v xl = *reinterpret_cast<const short8v*>(&xcL[lr][lg * 8]);

    f32x4 zz[2];
#pragma unroll
    for (int tau = 0; tau < 2; ++tau) {
      f32x4 z = MFMA16(Bzh[tau], xh, b1v[tau]);   // A=w1 (m=h), B=xc (n=sample)
      z = MFMA16(Bzh[tau], xl, z);
      z = MFMA16(Bzl[tau], xh, z);
      zz[tau] = z;                                 // z' = z * log2e
    }
    float q = 0.0f;
    unsigned short ab[2][4];
#pragma unroll
    for (int tau = 0; tau < 2; ++tau)
#pragma unroll
      for (int r = 0; r < 4; ++r) {
        float E = __builtin_amdgcn_exp2f(-zz[tau][r]);      // 2^(-z') = e^(-z)
        float t = __builtin_amdgcn_rcpf(1.0f + E);          // sigmoid
        q = fmaf(t * t * E, w2cv[tau][r], q);               // s(1-s) * w2*c
        ab[tau][r] = bf16rne(t * w2v[tau][r]);              // a = s*w2 (bf16)
      }
    lapAcc = fmaf(wa, q, lapAcc);
    short8v aF;                                             // sigma-ordered A-frag
#pragma unroll
    for (int j = 0; j < 8; ++j) aF[j] = (short)ab[j >> 2][j & 3];

    // -- phase 2: g-MFMAs straight from registers, partG write ------------------
#pragma unroll
    for (int nu = 0; nu < 2; ++nu) {
      f32x4 g = {0.0f, 0.0f, 0.0f, 0.0f};
      g = MFMA16(aF, Bgh[nu], g);
      g = MFMA16(aF, Bgl[nu], g);
#pragma unroll
      for (int r = 0; r < 4; ++r)
        partG[wv][lg * 4 + r][nu * 16 + lr] = g[r];
    }
    __syncthreads();                     // barrier 1: partG ready

    // -- phase 3: owner-thread reduce, state update, pair-packed xc write -------
    float p0 = partG[0][s_own][d_own], p1 = partG[1][s_own][d_own];
    float p2 = partG[2][s_own][d_own], p3 = partG[3][s_own][d_own];
    float p4 = partG[4][s_own][d_own], p5 = partG[5][s_own][d_own];
    float p6 = partG[6][s_own][d_own], p7 = partG[7][s_own][d_own];
    float gsum = ((p0 + p1) + (p2 + p3)) + ((p4 + p5) + (p6 + p7));
    accr = fmaf(wa, gsum, accr);
    float xw;
    if (st < 3) {
      xw = fmaf(wc, gsum, x0r);
    } else {
      x0r += accr; accr = 0.0f; xw = x0r;
    }
    {
      unsigned u = __float_as_uint(xw);
      xcH[s_own][xci] = (unsigned short)(u >> 16);
      float res = xw - __uint_as_float(u & 0xFFFF0000u);    // exact
      xcL[s_own][xci] = (unsigned short)(__float_as_uint(res) >> 16);
    }
    __syncthreads();                     // barrier 2: xc ready (+ partG WAR)
  }

  // ---------------- final laplacian reduce (once) --------------------------------
  lapAcc += __shfl_xor(lapAcc, 16);      // sum over the 4 lg groups
  lapAcc += __shfl_xor(lapAcc, 32);
  if (l < 16) partG[wv][lr][0] = lapAcc; // per-wave partial for sample lr
  __syncthreads();

  // ---------------- output --------------------------------------------------------
  if (tid < SPB * D) out[blockIdx.x * (SPB * D) + tid] = x0r;   // coalesced
  if (tid < SPB) {
    float lt = 0.0f;
#pragma unroll
    for (int w = 0; w < NW; ++w) lt += partG[w][tid][0];
    out[B_TOTAL * D + blockIdx.x * SPB + tid] = lp - lt;
  }
}

extern "C" void kernel_launch(void* const* d_in, const int* in_sizes, int n_in,
                              void* d_out, int out_size, void* d_ws, size_t ws_size,
                              hipStream_t stream) {
  const float* x    = (const float*)d_in[0];
  const float* logp = (const float*)d_in[1];
  const float* w1   = (const float*)d_in[2];
  const float* b1   = (const float*)d_in[3];
  const float* w2   = (const float*)d_in[4];
  // d_in[5] (b2) shifts u only; it does not affect grad_u or the laplacian.
  float* out = (float*)d_out;

  ma_flow_kernel<<<B_TOTAL / SPB, 512, 0, stream>>>(x, logp, w1, b1, w2, out);
}

// Round 16
// 13.272 us; speedup vs baseline: 1.4309x; 1.4309x over previous
//
#include <hip/hip_runtime.h>

#define B_TOTAL 4096
#define D 32
#define H 256
#define SPB 16           // samples per block (= MFMA M/N)
#define NW 8             // waves per block
#define HPW 32           // hidden units per wave
#define PGS 34           // partG row stride (dwords)
#define XCS 40           // xcH/xcL row stride (u16)

static constexpr float EPS = 0.1f;
static constexpr float LOG2E = 1.44269504088896340736f;

typedef __attribute__((ext_vector_type(8))) short short8v;   // 8 x bf16
typedef __attribute__((ext_vector_type(4))) float f32x4;

__device__ __forceinline__ unsigned short bf16rne(float f) {
  unsigned u = __float_as_uint(f);
  u += 0x7FFFu + ((u >> 16) & 1u);
  return (unsigned short)(u >> 16);
}

#define MFMA16(A, Bf, C) __builtin_amdgcn_mfma_f32_16x16x32_bf16((A), (Bf), (C), 0, 0, 0)

// k-permutations (MFMA contracts K in any order as long as A and B agree):
//   kappa(lg*8+j) = lg*4 + (j>>1) + ((j&1)<<4)   [z-pass k=d; matches xc pair layout]
//   sigma(lg*8+j) = ((j>>2)<<4) + lg*4 + (j&3)   [g-pass k=h; matches in-register a layout]

__global__ __launch_bounds__(512, 2) void ma_flow_kernel(
    const float* __restrict__ x_in, const float* __restrict__ logp_in,
    const float* __restrict__ w1, const float* __restrict__ b1,
    const float* __restrict__ w2, float* __restrict__ out)
{
  __shared__ __align__(16) float partG[NW][SPB][PGS];        // per-wave partial g
  __shared__ __align__(16) unsigned short xcH[SPB][XCS];     // xc hi-bf16, pair layout
  __shared__ __align__(16) unsigned short xcL[SPB][XCS];     // xc lo-bf16, pair layout

  const int tid = threadIdx.x;
  const int l  = tid & 63;
  const int wv = tid >> 6;       // wave id = 32-h slice
  const int lr = l & 15;         // MFMA index lane: sample (z-out/g-A); d-col (Bg)
  const int lg = l >> 4;         // MFMA k-group
  const int hbase = wv * HPW;
  const int s_own = tid >> 5;    // owned sample
  const int d_own = tid & 31;    // owned dim
  const int xci = ((d_own & 15) << 1) | (d_own >> 4);  // u16 index in pair layout

  // ---------------- weight fragments (registers, single bf16) -------------------
  // z-pass A=w1*log2e: A[m=h][k=d], h = hbase + tau*16 + lr, kappa k-order
  short8v Bzh[2];
  float ctau[2];
#pragma unroll
  for (int tau = 0; tau < 2; ++tau) {
    const int h = hbase + tau * 16 + lr;
    float cpart = 0.0f;
    short8v hi;
#pragma unroll
    for (int j = 0; j < 8; ++j) {
      const int dj = lg * 4 + (j >> 1) + ((j & 1) << 4);   // kappa
      float w = w1[dj * H + h];
      cpart = fmaf(w, w, cpart);                           // c_h from TRUE w
      hi[j] = (short)bf16rne(w * LOG2E);                   // scaled for exp2
    }
    Bzh[tau] = hi;
    cpart += __shfl_xor(cpart, 16);            // sum the 4 k-groups -> c_h (h by lr)
    cpart += __shfl_xor(cpart, 32);
    ctau[tau] = cpart;
  }
  // per-lane h-tables for the swapped z output: h = hbase + tau*16 + lg*4 + r
  f32x4 b1v[2], w2v[2], w2cv[2];
#pragma unroll
  for (int tau = 0; tau < 2; ++tau)
#pragma unroll
    for (int r = 0; r < 4; ++r) {
      const int hh = hbase + tau * 16 + lg * 4 + r;
      b1v[tau][r] = b1[hh] * LOG2E;                        // scaled bias
      float w2x = w2[hh];
      w2v[tau][r] = w2x;
      w2cv[tau][r] = w2x * __shfl(ctau[tau], lg * 4 + r);  // c redistributed lr->(lg,r)
    }
  // g-pass B=w1^T (TRUE weights, single bf16): B[k=h][n=d], d = nu*16 + lr, sigma
  short8v Bgh[2];
#pragma unroll
  for (int nu = 0; nu < 2; ++nu) {
    const int d = nu * 16 + lr;
    short8v hi;
#pragma unroll
    for (int j = 0; j < 8; ++j) {
      const int hl = ((j >> 2) << 4) + lg * 4 + (j & 3);   // sigma
      hi[j] = (short)bf16rne(w1[d * H + hbase + hl]);
    }
    Bgh[nu] = hi;
  }

  // ---------------- state init: thread owns (s_own, d_own) ----------------------
  float x0r = x_in[blockIdx.x * (SPB * D) + tid];   // coalesced
  float accr = 0.0f;
  {
    unsigned u = __float_as_uint(x0r);
    xcH[s_own][xci] = (unsigned short)(u >> 16);
    float res = x0r - __uint_as_float(u & 0xFFFF0000u);   // exact
    xcL[s_own][xci] = (unsigned short)(__float_as_uint(res) >> 16);
  }
  float lp = (tid < SPB) ? logp_in[blockIdx.x * SPB + tid] : 0.0f;
  float lapAcc = 0.0f;     // wa-weighted lap partial for sample lr (this lane's 8 h's)
  __syncthreads();

  // ---------------- 8 RK4 stage evaluations -------------------------------------
#pragma unroll 1
  for (int stage = 0; stage < 8; ++stage) {
    const int st = stage & 3;
    const float wa = (st == 0 || st == 3) ? (EPS / 6.0f) : (EPS / 3.0f);
    const float wc = (st == 2) ? EPS : (EPS * 0.5f);

    // -- phase 1: swapped z-MFMAs (D[m=h][n=sample]) + sigmoid, in-register -----
    short8v xh = *reinterpret_cast<const short8v*>(&xcH[lr][lg * 8]);
    short8v xl = *reinterpret_cast<const short8v*>(&xcL[lr][lg * 8]);

    f32x4 zz[2];
#pragma unroll
    for (int tau = 0; tau < 2; ++tau) {
      f32x4 z = MFMA16(Bzh[tau], xh, b1v[tau]);   // A=w1 (m=h), B=xc (n=sample)
      z = MFMA16(Bzh[tau], xl, z);
      zz[tau] = z;                                 // z' = z * log2e
    }
    float q = 0.0f;
    unsigned short ab[2][4];
#pragma unroll
    for (int tau = 0; tau < 2; ++tau)
#pragma unroll
      for (int r = 0; r < 4; ++r) {
        float E = __builtin_amdgcn_exp2f(-zz[tau][r]);      // 2^(-z') = e^(-z)
        float t = __builtin_amdgcn_rcpf(1.0f + E);          // sigmoid
        q = fmaf(t * t * E, w2cv[tau][r], q);               // s(1-s) * w2*c
        ab[tau][r] = bf16rne(t * w2v[tau][r]);              // a = s*w2 (bf16)
      }
    lapAcc = fmaf(wa, q, lapAcc);
    short8v aF;                                             // sigma-ordered A-frag
#pragma unroll
    for (int j = 0; j < 8; ++j) aF[j] = (short)ab[j >> 2][j & 3];

    // -- phase 2: g-MFMAs straight from registers, partG write ------------------
#pragma unroll
    for (int nu = 0; nu < 2; ++nu) {
      f32x4 g = {0.0f, 0.0f, 0.0f, 0.0f};
      g = MFMA16(aF, Bgh[nu], g);
#pragma unroll
      for (int r = 0; r < 4; ++r)
        partG[wv][lg * 4 + r][nu * 16 + lr] = g[r];
    }
    __syncthreads();                     // barrier 1: partG ready

    // -- phase 3: owner-thread reduce, state update, pair-packed xc write -------
    float p0 = partG[0][s_own][d_own], p1 = partG[1][s_own][d_own];
    float p2 = partG[2][s_own][d_own], p3 = partG[3][s_own][d_own];
    float p4 = partG[4][s_own][d_own], p5 = partG[5][s_own][d_own];
    float p6 = partG[6][s_own][d_own], p7 = partG[7][s_own][d_own];
    float gsum = ((p0 + p1) + (p2 + p3)) + ((p4 + p5) + (p6 + p7));
    accr = fmaf(wa, gsum, accr);
    float xw;
    if (st < 3) {
      xw = fmaf(wc, gsum, x0r);
    } else {
      x0r += accr; accr = 0.0f; xw = x0r;
    }
    {
      unsigned u = __float_as_uint(xw);
      xcH[s_own][xci] = (unsigned short)(u >> 16);
      float res = xw - __uint_as_float(u & 0xFFFF0000u);    // exact
      xcL[s_own][xci] = (unsigned short)(__float_as_uint(res) >> 16);
    }
    __syncthreads();                     // barrier 2: xc ready (+ partG WAR)
  }

  // ---------------- final laplacian reduce (once) --------------------------------
  lapAcc += __shfl_xor(lapAcc, 16);      // sum over the 4 lg groups
  lapAcc += __shfl_xor(lapAcc, 32);
  if (l < 16) partG[wv][lr][0] = lapAcc; // per-wave partial for sample lr
  __syncthreads();

  // ---------------- output --------------------------------------------------------
  out[blockIdx.x * (SPB * D) + tid] = x0r;             // coalesced
  if (tid < SPB) {
    float lt = 0.0f;
#pragma unroll
    for (int w = 0; w < NW; ++w) lt += partG[w][tid][0];
    out[B_TOTAL * D + blockIdx.x * SPB + tid] = lp - lt;
  }
}

extern "C" void kernel_launch(void* const* d_in, const int* in_sizes, int n_in,
                              void* d_out, int out_size, void* d_ws, size_t ws_size,
                              hipStream_t stream) {
  const float* x    = (const float*)d_in[0];
  const float* logp = (const float*)d_in[1];
  const float* w1   = (const float*)d_in[2];
  const float* b1   = (const float*)d_in[3];
  const float* w2   = (const float*)d_in[4];
  // d_in[5] (b2) shifts u only; it does not affect grad_u or the laplacian.
  float* out = (float*)d_out;

  ma_flow_kernel<<<B_TOTAL / SPB, 512, 0, stream>>>(x, logp, w1, b1, w2, out);
}

// Round 17
// 13.126 us; speedup vs baseline: 1.4469x; 1.0112x over previous
//
#include <hip/hip_runtime.h>

#define B_TOTAL 4096
#define D 32
#define H 256
#define SPB 16           // samples per block (= MFMA M/N)
#define NW 8             // waves per block
#define HPW 32           // hidden units per wave
#define PGS 34           // partG row stride (dwords)
#define XCS 40           // xcB row stride (u16)

static constexpr float EPS = 0.1f;
static constexpr float LOG2E = 1.44269504088896340736f;

typedef __attribute__((ext_vector_type(8))) short short8v;   // 8 x bf16
typedef __attribute__((ext_vector_type(4))) float f32x4;

__device__ __forceinline__ unsigned short bf16rne(float f) {
  unsigned u = __float_as_uint(f);
  u += 0x7FFFu + ((u >> 16) & 1u);
  return (unsigned short)(u >> 16);
}

#define MFMA16(A, Bf, C) __builtin_amdgcn_mfma_f32_16x16x32_bf16((A), (Bf), (C), 0, 0, 0)

// k-permutations (MFMA contracts K in any order as long as A and B agree):
//   kappa(lg*8+j) = lg*4 + (j>>1) + ((j&1)<<4)   [z-pass k=d; matches xc pair layout]
//   sigma(lg*8+j) = ((j>>2)<<4) + lg*4 + (j&3)   [g-pass k=h; matches in-register a layout]

__global__ __launch_bounds__(512, 2) void ma_flow_kernel(
    const float* __restrict__ x_in, const float* __restrict__ logp_in,
    const float* __restrict__ w1, const float* __restrict__ b1,
    const float* __restrict__ w2, float* __restrict__ out)
{
  __shared__ __align__(16) float partG[NW][SPB][PGS];        // per-wave partial g
  __shared__ __align__(16) unsigned short xcB[SPB][XCS];     // xc bf16 (RNE), pair layout

  const int tid = threadIdx.x;
  const int l  = tid & 63;
  const int wv = tid >> 6;       // wave id = 32-h slice
  const int lr = l & 15;         // MFMA index lane: sample (z-out/g-A); d-col (Bg)
  const int lg = l >> 4;         // MFMA k-group
  const int hbase = wv * HPW;
  const int s_own = tid >> 5;    // owned sample
  const int d_own = tid & 31;    // owned dim
  const int xci = ((d_own & 15) << 1) | (d_own >> 4);  // u16 index in pair layout

  // ---------------- weight fragments (registers, single bf16) -------------------
  // z-pass A=w1*log2e: A[m=h][k=d], h = hbase + tau*16 + lr, kappa k-order
  short8v Bzh[2];
  float ctau[2];
#pragma unroll
  for (int tau = 0; tau < 2; ++tau) {
    const int h = hbase + tau * 16 + lr;
    float cpart = 0.0f;
    short8v hi;
#pragma unroll
    for (int j = 0; j < 8; ++j) {
      const int dj = lg * 4 + (j >> 1) + ((j & 1) << 4);   // kappa
      float w = w1[dj * H + h];
      cpart = fmaf(w, w, cpart);                           // c_h from TRUE w
      hi[j] = (short)bf16rne(w * LOG2E);                   // scaled for exp2
    }
    Bzh[tau] = hi;
    cpart += __shfl_xor(cpart, 16);            // sum the 4 k-groups -> c_h (h by lr)
    cpart += __shfl_xor(cpart, 32);
    ctau[tau] = cpart;
  }
  // per-lane h-tables for the swapped z output: h = hbase + tau*16 + lg*4 + r
  f32x4 b1v[2], w2v[2], w2cv[2];
#pragma unroll
  for (int tau = 0; tau < 2; ++tau)
#pragma unroll
    for (int r = 0; r < 4; ++r) {
      const int hh = hbase + tau * 16 + lg * 4 + r;
      b1v[tau][r] = b1[hh] * LOG2E;                        // scaled bias
      float w2x = w2[hh];
      w2v[tau][r] = w2x;
      w2cv[tau][r] = w2x * __shfl(ctau[tau], lg * 4 + r);  // c redistributed lr->(lg,r)
    }
  // g-pass B=w1^T (TRUE weights, single bf16): B[k=h][n=d], d = nu*16 + lr, sigma
  short8v Bgh[2];
#pragma unroll
  for (int nu = 0; nu < 2; ++nu) {
    const int d = nu * 16 + lr;
    short8v hi;
#pragma unroll
    for (int j = 0; j < 8; ++j) {
      const int hl = ((j >> 2) << 4) + lg * 4 + (j & 3);   // sigma
      hi[j] = (short)bf16rne(w1[d * H + hbase + hl]);
    }
    Bgh[nu] = hi;
  }

  // ---------------- state init: thread owns (s_own, d_own) ----------------------
  float x0r = x_in[blockIdx.x * (SPB * D) + tid];   // coalesced
  float accr = 0.0f;
  xcB[s_own][xci] = bf16rne(x0r);
  float lp = (tid < SPB) ? logp_in[blockIdx.x * SPB + tid] : 0.0f;
  float lapAcc = 0.0f;     // wa-weighted lap partial for sample lr (this lane's 8 h's)
  __syncthreads();

  // ---------------- 8 RK4 stage evaluations -------------------------------------
#pragma unroll 1
  for (int stage = 0; stage < 8; ++stage) {
    const int st = stage & 3;
    const float wa = (st == 0 || st == 3) ? (EPS / 6.0f) : (EPS / 3.0f);
    const float wc = (st == 2) ? EPS : (EPS * 0.5f);

    // -- phase 1: swapped z-MFMAs (D[m=h][n=sample]) + sigmoid, in-register -----
    short8v xh = *reinterpret_cast<const short8v*>(&xcB[lr][lg * 8]);

    f32x4 zz[2];
#pragma unroll
    for (int tau = 0; tau < 2; ++tau)
      zz[tau] = MFMA16(Bzh[tau], xh, b1v[tau]);   // A=w1 (m=h), B=xc (n=sample)

    float q = 0.0f;
    unsigned short ab[2][4];
#pragma unroll
    for (int tau = 0; tau < 2; ++tau)
#pragma unroll
      for (int r = 0; r < 4; ++r) {
        float E = __builtin_amdgcn_exp2f(-zz[tau][r]);      // 2^(-z') = e^(-z)
        float t = __builtin_amdgcn_rcpf(1.0f + E);          // sigmoid
        q = fmaf(t * t * E, w2cv[tau][r], q);               // s(1-s) * w2*c
        ab[tau][r] = bf16rne(t * w2v[tau][r]);              // a = s*w2 (bf16)
      }
    lapAcc = fmaf(wa, q, lapAcc);
    short8v aF;                                             // sigma-ordered A-frag
#pragma unroll
    for (int j = 0; j < 8; ++j) aF[j] = (short)ab[j >> 2][j & 3];

    // -- phase 2: g-MFMAs straight from registers, partG write ------------------
#pragma unroll
    for (int nu = 0; nu < 2; ++nu) {
      f32x4 g = {0.0f, 0.0f, 0.0f, 0.0f};
      g = MFMA16(aF, Bgh[nu], g);
#pragma unroll
      for (int r = 0; r < 4; ++r)
        partG[wv][lg * 4 + r][nu * 16 + lr] = g[r];
    }
    __syncthreads();                     // barrier 1: partG ready

    // -- phase 3: owner-thread reduce, state update, bf16 xc write --------------
    float p0 = partG[0][s_own][d_own], p1 = partG[1][s_own][d_own];
    float p2 = partG[2][s_own][d_own], p3 = partG[3][s_own][d_own];
    float p4 = partG[4][s_own][d_own], p5 = partG[5][s_own][d_own];
    float p6 = partG[6][s_own][d_own], p7 = partG[7][s_own][d_own];
    float gsum = ((p0 + p1) + (p2 + p3)) + ((p4 + p5) + (p6 + p7));
    accr = fmaf(wa, gsum, accr);
    if (st < 3) {
      xcB[s_own][xci] = bf16rne(fmaf(wc, gsum, x0r));
    } else {
      x0r += accr; accr = 0.0f;
      if (stage != 7) xcB[s_own][xci] = bf16rne(x0r);   // dead on final stage
    }
    __syncthreads();                     // barrier 2: xc ready (+ partG WAR)
  }

  // ---------------- final laplacian reduce (once) --------------------------------
  lapAcc += __shfl_xor(lapAcc, 16);      // sum over the 4 lg groups
  lapAcc += __shfl_xor(lapAcc, 32);
  if (l < 16) partG[wv][lr][0] = lapAcc; // per-wave partial for sample lr
  __syncthreads();

  // ---------------- output --------------------------------------------------------
  out[blockIdx.x * (SPB * D) + tid] = x0r;             // coalesced
  if (tid < SPB) {
    float lt = 0.0f;
#pragma unroll
    for (int w = 0; w < NW; ++w) lt += partG[w][tid][0];
    out[B_TOTAL * D + blockIdx.x * SPB + tid] = lp - lt;
  }
}

extern "C" void kernel_launch(void* const* d_in, const int* in_sizes, int n_in,
                              void* d_out, int out_size, void* d_ws, size_t ws_size,
                              hipStream_t stream) {
  const float* x    = (const float*)d_in[0];
  const float* logp = (const float*)d_in[1];
  const float* w1   = (const float*)d_in[2];
  const float* b1   = (const float*)d_in[3];
  const float* w2   = (const float*)d_in[4];
  // d_in[5] (b2) shifts u only; it does not affect grad_u or the laplacian.
  float* out = (float*)d_out;

  ma_flow_kernel<<<B_TOTAL / SPB, 512, 0, stream>>>(x, logp, w1, b1, w2, out);
}